// Round 14
// baseline (107.790 us; speedup 1.0000x reference)
//
#include <hip/hip_runtime.h>
#include <hip/hip_bf16.h>

// Problem constants
#define B_SZ   16
#define V_IN   1024
#define V_OUT  4096
#define C_IN   128
#define C_OUT  256
#define K_NB   18
#define NNZ    16384
#define K_GEMM (K_NB * C_IN)   // 2304
#define BK     64
#define NKT    (K_GEMM / BK)   // 36

typedef __attribute__((ext_vector_type(8))) short bf16x8;   // 8 bf16 = 4 VGPRs
typedef __attribute__((ext_vector_type(4))) float f32x4;

#define GLOAD16(src, dst) __builtin_amdgcn_global_load_lds( \
    (const __attribute__((address_space(1))) unsigned int*)(src), \
    (__attribute__((address_space(3))) unsigned int*)(dst), 16, 0, 0)

#define MFMA16(a_, b_, c_) __builtin_amdgcn_mfma_f32_16x16x32_bf16((a_), (b_), (c_), 0, 0, 0)

// ---------------- fused hist + combined-weight kernel ----------------
// blocks 0..63: histogram of rows. blocks 64..207: weight fragment images. block 208: bias.
// wTs layout (fragment-major): wTs[kt][nt][ks][lane][e]  (nt=col/16, ks=k32, lane=MFMA lane)
// lane l holds B[col=nt*16+(l&15)][k=kt*64+ks*32+(l>>4)*8+e] -> a wave's read is 1KB contiguous.
__global__ __launch_bounds__(256) void hist_wcomb_kernel(
    const int* __restrict__ rows, int* __restrict__ counts,
    const float* __restrict__ W1, const float* __restrict__ Wd3,
    const float* __restrict__ W2d3, const float* __restrict__ Wf,
    const float* __restrict__ b1, const float* __restrict__ bd3,
    const float* __restrict__ b2d3, const float* __restrict__ bf,
    __hip_bfloat16* __restrict__ wTs, float* __restrict__ bias) {
    const int t = threadIdx.x;
    if (blockIdx.x < 64) {                    // histogram part
        int n = blockIdx.x * 256 + t;
        atomicAdd(&counts[rows[n]], 1);
        return;
    }
    const int blk = blockIdx.x - 64;
    if (blk == NKT * 4) {                     // bias block
        float v = b1[t];
        if (t < 128)      v += bf[t];
        else if (t < 192) v += b2d3[t - 128];
        else              v += bd3[t - 192];
        bias[t] = v;
        return;
    }
    const int kt = blk >> 2, part = blk & 3;  // part = 64-col quadrant
    __shared__ __hip_bfloat16 img[4096];      // 4 nt x 2 ks x 64 lane x 8 e
    const int k0 = kt * 64;

    // element (cl in [0,64), kl in [0,64)) -> fragment-major local index
    auto put = [&](int cl, int kl, float v) {
        int ks   = kl >> 5;
        int lane = (cl & 15) | (((kl >> 3) & 3) << 4);
        int e    = kl & 7;
        int idx  = ((cl >> 4) << 10) | (ks << 9) | (lane << 3) | e;
        img[idx] = __float2bfloat16(v);
    };

    if (part < 2) {
        const int cbase = part << 6;                 // cols 0..63 or 64..127 (Wf)
        for (int i = t; i < 4096; i += 256) {
            int kl = i >> 6, cl = i & 63;
            int col = cbase + cl, r = k0 + kl;
            float v = Wf[r * 128 + col];
            if (r < 128) v += W1[r * 256 + col];
            put(cl, kl, v);
        }
    } else if (part == 2) {                          // cols 128..191 (W2d3, r<1536)
        for (int i = t; i < 4096; i += 256) {
            int kl = i >> 6, cl = i & 63;
            int r = k0 + kl;
            float v = (r < 1536) ? W2d3[r * 64 + cl] : 0.f;
            if (r < 128) v += W1[r * 256 + 128 + cl];
            put(cl, kl, v);
        }
    } else {                                         // cols 192..255 (Wd3, r<768)
        for (int i = t; i < 4096; i += 256) {
            int kl = i >> 6, cl = i & 63;
            int r = k0 + kl;
            float v = (r < 768) ? Wd3[r * 64 + cl] : 0.f;
            if (r < 128) v += W1[r * 256 + 192 + cl];
            put(cl, kl, v);
        }
    }
    __syncthreads();
    // linear dump: 8 KB quadrant (nt-major matches global fragment order)
    ulonglong2* dst = (ulonglong2*)(wTs + (size_t)kt * 16384 + part * 4096);
    const ulonglong2* srcv = (const ulonglong2*)img;
#pragma unroll
    for (int i = t; i < 512; i += 256) dst[i] = srcv[i];
}

// 1024 threads, shfl-based scan of 4096 counts (4 per thread), 1 barrier
__global__ void scan_kernel(const int* __restrict__ counts, int* offsets, int* cursor) {
    __shared__ int wsum[16];
    int t = threadIdx.x;
    int lane = t & 63, wid = t >> 6;
    int base4 = t * 4;
    int c0 = counts[base4], c1 = counts[base4 + 1], c2 = counts[base4 + 2], c3 = counts[base4 + 3];
    int tot = c0 + c1 + c2 + c3;
    int v = tot;
#pragma unroll
    for (int d = 1; d < 64; d <<= 1) {
        int u = __shfl_up(v, d);
        if (lane >= d) v += u;
    }
    if (lane == 63) wsum[wid] = v;
    __syncthreads();
    int wbase = 0;
#pragma unroll
    for (int w = 0; w < 16; ++w) wbase += (w < wid) ? wsum[w] : 0;
    int incl = wbase + v;
    int excl = incl - tot;
    offsets[base4]     = excl;
    offsets[base4 + 1] = excl + c0;
    offsets[base4 + 2] = excl + c0 + c1;
    offsets[base4 + 3] = excl + c0 + c1 + c2;
    cursor[base4]     = excl;
    cursor[base4 + 1] = excl + c0;
    cursor[base4 + 2] = excl + c0 + c1;
    cursor[base4 + 3] = excl + c0 + c1 + c2;
    if (t == 1023) offsets[V_OUT] = incl;
}

// fill: scatter packed (col,val) pairs in CSR order
__global__ void fill_kernel(const int* __restrict__ rows, const int* __restrict__ cols,
                            const float* __restrict__ vals, int* cursor,
                            float2* __restrict__ pcv) {
    int n = blockIdx.x * blockDim.x + threadIdx.x;
    if (n < NNZ) {
        int r = rows[n];
        int pos = atomicAdd(&cursor[r], 1);
        pcv[pos] = make_float2(__int_as_float(cols[n]), vals[n]);
    }
}

// ---------------- pooling: block = out-row, threads = (batch 16) x (c4 32) ----------------
__global__ __launch_bounds__(512) void pool_kernel(
    const float* __restrict__ x, const int* __restrict__ offsets,
    const float2* __restrict__ pcv, __hip_bfloat16* __restrict__ pool) {
    int r = blockIdx.x;
    int t = threadIdx.x;
    int b = t >> 5, c4 = t & 31;
    int j0 = offsets[r], j1 = offsets[r + 1];
    const float4* xb = (const float4*)x + (size_t)b * (V_IN * 32);
    float4 acc = {0.f, 0.f, 0.f, 0.f};
    for (int j = j0; j < j1; ++j) {
        float2 cv = pcv[j];
        int col = __float_as_int(cv.x);
        float v = cv.y;
        float4 xv = xb[col * 32 + c4];
        acc.x += v * xv.x; acc.y += v * xv.y; acc.z += v * xv.z; acc.w += v * xv.w;
    }
    ushort4 o;
    o.x = __builtin_bit_cast(unsigned short, __float2bfloat16(acc.x));
    o.y = __builtin_bit_cast(unsigned short, __float2bfloat16(acc.y));
    o.z = __builtin_bit_cast(unsigned short, __float2bfloat16(acc.z));
    o.w = __builtin_bit_cast(unsigned short, __float2bfloat16(acc.w));
    ((ushort4*)pool)[((size_t)b * V_OUT + r) * 32 + c4] = o;
}

// ---------------- gathered GEMM: 256x256 tile, 16 waves, balanced K-skip.
// A: LDS 3-slot, 1 barrier/K-tile. B: coalesced register loads from fragment-major wTs
// (each wave reads contiguous 1KB per fragment; no B LDS traffic at all). ----------------
__global__ __launch_bounds__(1024, 4) void gemm_kernel(
    const __hip_bfloat16* __restrict__ pool,    // [16][4096][128] bf16
    const __hip_bfloat16* __restrict__ wTs,     // [36][16][2][64][8] bf16 fragment-major
    const float* __restrict__ bias,             // [256]
    const int* __restrict__ spiral,             // [4096][18]
    float* __restrict__ out)                    // [16][4096][256] f32
{
    // LDS: A slots @0, 32768, 65536 ; spiral cache @98304 (18432B)
    __shared__ __align__(16) char smem[116736];
    int* spl = (int*)(smem + 98304);

    const int tid  = threadIdx.x;
    const int lane = tid & 63;
    const int wid  = tid >> 6;          // 0..15
    const int wc   = wid & 3;
    const int wm   = (wid >> 2) << 6;   // 0,64,128,192

    const int bid = blockIdx.x;
    const int bm  = ((bid & 7) << 5) + (bid >> 3);   // bijective XCD swizzle (256 = 8*32)
    const int b   = bm >> 4;                          // batch
    const int v0  = (bm & 15) << 8;                   // m-tile origin within batch

    // cache this block's spiral rows in LDS: 256 rows x 18
    for (int i = tid; i < 256 * K_NB; i += 1024) spl[i] = spiral[v0 * K_NB + i];
    asm volatile("s_waitcnt vmcnt(0) lgkmcnt(0)" ::: "memory");
    __builtin_amdgcn_s_barrier();

    const char* poolBytes = (const char*)(pool + (size_t)b * V_OUT * C_IN);
    const char* wTsBytes  = (const char*)wTs;
    // inverse-swizzled source column byte (identical for both 1024-chunks)
    const int sb = ((tid & 7) << 4) ^ (((tid >> 3) & 7) << 4);

    auto stageA = [&](int kt, int slot) {          // 2 vmem loads
        const int j   = kt >> 1;
        const int c0b = (kt & 1) << 7;
        char* dst = smem + slot * 32768;
#pragma unroll
        for (int ch = 0; ch < 2; ++ch) {
            int flat = (ch << 10) + tid;
            int sidx = spl[(flat >> 3) * K_NB + j];
            GLOAD16(poolBytes + ((size_t)sidx << 8) + (c0b + sb), dst + flat * 16);
        }
    };

    // per-lane fragment-read constants
    const int l15   = lane & 15;
    const int swm   = (lane & 7) << 4;          // frag-row&7 == lane&7
    const int klane = (lane >> 4) << 4;         // 0,16,32,48 (byte)
    const int kk0   = klane ^ swm;
    const int kk1   = (64 + klane) ^ swm;
    const int aBase = (wm + l15) << 7;
    const int fOff  = lane << 4;                // coalesced fragment byte offset
    const int nt0B  = (2 * wc)     * 2048;      // full col-tile 0 fragment base
    const int nt1B  = (2 * wc + 1) * 2048;      // full col-tile 1
    const int nt2B  = (8 + wc)     * 2048;      // mid (kt<24)
    const int nt3B  = (12 + wc)    * 2048;      // short (kt<12)

    f32x4 acc[4][4] = {};

    stageA(0, 0);

    int sl = 0;
    for (int kt = 0; kt < NKT; ++kt) {
        const char* As  = smem + sl * 32768;
        const char* wKt = wTsBytes + ((size_t)kt << 15);
        const bool doMid = kt < 24, doShort = kt < 12;

        // B fragment register loads — coalesced 1KB/wave, stay in flight across barrier
        bf16x8 b00, b01, b02, b03, b10, b11, b12, b13;
        b00 = *(const bf16x8*)(wKt + nt0B + fOff);
        b01 = *(const bf16x8*)(wKt + nt1B + fOff);
        b10 = *(const bf16x8*)(wKt + nt0B + 1024 + fOff);
        b11 = *(const bf16x8*)(wKt + nt1B + 1024 + fOff);
        if (doMid)   { b02 = *(const bf16x8*)(wKt + nt2B + fOff);
                       b12 = *(const bf16x8*)(wKt + nt2B + 1024 + fOff); }
        if (doShort) { b03 = *(const bf16x8*)(wKt + nt3B + fOff);
                       b13 = *(const bf16x8*)(wKt + nt3B + 1024 + fOff); }

        int nsl = sl + 1; if (nsl == 3) nsl = 0;
        if (kt + 1 < NKT) {
            stageA(kt + 1, nsl);
            // queue: [A(kt)x2 oldest, B xnB, A(kt+1)x2] -> wait A(kt) = leave nB+2
            if (doShort)      asm volatile("s_waitcnt vmcnt(10)" ::: "memory");
            else if (doMid)   asm volatile("s_waitcnt vmcnt(8)"  ::: "memory");
            else              asm volatile("s_waitcnt vmcnt(6)"  ::: "memory");
        } else {
            asm volatile("s_waitcnt vmcnt(4)" ::: "memory");   // leave the 4 B loads
        }
        __builtin_amdgcn_s_barrier();      // A(kt) visible to all waves; slot-overwrite safe (3 slots)
        __builtin_amdgcn_sched_barrier(0);

        // ================= ks = 0 =================
        {
            bf16x8 a0 = *(const bf16x8*)(As + aBase + (0 << 11) + kk0);
            bf16x8 a1 = *(const bf16x8*)(As + aBase + (1 << 11) + kk0);
            bf16x8 a2 = *(const bf16x8*)(As + aBase + (2 << 11) + kk0);
            bf16x8 a3 = *(const bf16x8*)(As + aBase + (3 << 11) + kk0);
            __builtin_amdgcn_s_setprio(1);
            acc[0][0] = MFMA16(a0, b00, acc[0][0]);
            acc[1][0] = MFMA16(a1, b00, acc[1][0]);
            acc[2][0] = MFMA16(a2, b00, acc[2][0]);
            acc[3][0] = MFMA16(a3, b00, acc[3][0]);
            acc[0][1] = MFMA16(a0, b01, acc[0][1]);
            acc[1][1] = MFMA16(a1, b01, acc[1][1]);
            acc[2][1] = MFMA16(a2, b01, acc[2][1]);
            acc[3][1] = MFMA16(a3, b01, acc[3][1]);
            __builtin_amdgcn_s_setprio(0);
            if (doMid) {
                __builtin_amdgcn_s_setprio(1);
                acc[0][2] = MFMA16(a0, b02, acc[0][2]);
                acc[1][2] = MFMA16(a1, b02, acc[1][2]);
                acc[2][2] = MFMA16(a2, b02, acc[2][2]);
                acc[3][2] = MFMA16(a3, b02, acc[3][2]);
                __builtin_amdgcn_s_setprio(0);
            }
            if (doShort) {
                __builtin_amdgcn_s_setprio(1);
                acc[0][3] = MFMA16(a0, b03, acc[0][3]);
                acc[1][3] = MFMA16(a1, b03, acc[1][3]);
                acc[2][3] = MFMA16(a2, b03, acc[2][3]);
                acc[3][3] = MFMA16(a3, b03, acc[3][3]);
                __builtin_amdgcn_s_setprio(0);
            }
        }
        // ================= ks = 1 =================
        {
            bf16x8 a0 = *(const bf16x8*)(As + aBase + (0 << 11) + kk1);
            bf16x8 a1 = *(const bf16x8*)(As + aBase + (1 << 11) + kk1);
            bf16x8 a2 = *(const bf16x8*)(As + aBase + (2 << 11) + kk1);
            bf16x8 a3 = *(const bf16x8*)(As + aBase + (3 << 11) + kk1);
            __builtin_amdgcn_s_setprio(1);
            acc[0][0] = MFMA16(a0, b10, acc[0][0]);
            acc[1][0] = MFMA16(a1, b10, acc[1][0]);
            acc[2][0] = MFMA16(a2, b10, acc[2][0]);
            acc[3][0] = MFMA16(a3, b10, acc[3][0]);
            acc[0][1] = MFMA16(a0, b11, acc[0][1]);
            acc[1][1] = MFMA16(a1, b11, acc[1][1]);
            acc[2][1] = MFMA16(a2, b11, acc[2][1]);
            acc[3][1] = MFMA16(a3, b11, acc[3][1]);
            __builtin_amdgcn_s_setprio(0);
            if (doMid) {
                __builtin_amdgcn_s_setprio(1);
                acc[0][2] = MFMA16(a0, b12, acc[0][2]);
                acc[1][2] = MFMA16(a1, b12, acc[1][2]);
                acc[2][2] = MFMA16(a2, b12, acc[2][2]);
                acc[3][2] = MFMA16(a3, b12, acc[3][2]);
                __builtin_amdgcn_s_setprio(0);
            }
            if (doShort) {
                __builtin_amdgcn_s_setprio(1);
                acc[0][3] = MFMA16(a0, b13, acc[0][3]);
                acc[1][3] = MFMA16(a1, b13, acc[1][3]);
                acc[2][3] = MFMA16(a2, b13, acc[2][3]);
                acc[3][3] = MFMA16(a3, b13, acc[3][3]);
                __builtin_amdgcn_s_setprio(0);
            }
        }
        sl = nsl;
    }

    // epilogue: +bias, relu, store f32
    const int nt[4] = {2 * wc, 2 * wc + 1, 8 + wc, 12 + wc};
#pragma unroll
    for (int ni = 0; ni < 4; ++ni) {
        int col = (nt[ni] << 4) + l15;
        float bz = bias[col];
#pragma unroll
        for (int mi = 0; mi < 4; ++mi) {
            int row0 = v0 + wm + mi * 16 + ((lane >> 4) << 2);
#pragma unroll
            for (int r4 = 0; r4 < 4; ++r4) {
                float v = acc[mi][ni][r4] + bz;
                out[((size_t)(b * V_OUT + row0 + r4)) * C_OUT + col] = v > 0.f ? v : 0.f;
            }
        }
    }
}

extern "C" void kernel_launch(void* const* d_in, const int* in_sizes, int n_in,
                              void* d_out, int out_size, void* d_ws, size_t ws_size,
                              hipStream_t stream) {
    const float* x     = (const float*)d_in[0];
    const float* vals  = (const float*)d_in[1];
    const float* W1    = (const float*)d_in[2];
    const float* b1    = (const float*)d_in[3];
    const float* Wd3   = (const float*)d_in[4];
    const float* bd3   = (const float*)d_in[5];
    const float* W2d3  = (const float*)d_in[6];
    const float* b2d3  = (const float*)d_in[7];
    const float* Wf    = (const float*)d_in[8];
    const float* bf    = (const float*)d_in[9];
    const int*   rows  = (const int*)d_in[10];
    const int*   cols  = (const int*)d_in[11];
    const int*   spiral= (const int*)d_in[12];
    float* out = (float*)d_out;

    // workspace layout
    char* ws = (char*)d_ws;
    __hip_bfloat16* pool = (__hip_bfloat16*)ws;                              // 16,777,216 B
    __hip_bfloat16* wTs  = (__hip_bfloat16*)(ws + 16777216);                 //  1,179,648 B
    float* bias          = (float*)(ws + 16777216 + 1179648);                //      1,024 B
    int*   counts        = (int*)(ws + 16777216 + 1179648 + 1024);
    int*   offsets       = counts + V_OUT;          // V_OUT+1 ints
    int*   cursor        = offsets + V_OUT + 4;     // padded
    float2* pcv          = (float2*)(cursor + V_OUT);  // NNZ float2 (8B-aligned)

    hipMemsetAsync(counts, 0, V_OUT * sizeof(int), stream);
    hist_wcomb_kernel<<<64 + NKT * 4 + 1, 256, 0, stream>>>(
        rows, counts, W1, Wd3, W2d3, Wf, b1, bd3, b2d3, bf, wTs, bias);
    scan_kernel<<<1, 1024, 0, stream>>>(counts, offsets, cursor);
    fill_kernel<<<NNZ / 256, 256, 0, stream>>>(rows, cols, vals, cursor, pcv);
    pool_kernel<<<V_OUT, 512, 0, stream>>>(x, offsets, pcv, pool);
    gemm_kernel<<<256, 1024, 0, stream>>>(pool, wTs, bias, spiral, out);
}

// Round 15
// 103.669 us; speedup vs baseline: 1.0398x; 1.0398x over previous
//
#include <hip/hip_runtime.h>
#include <hip/hip_bf16.h>

// Problem constants
#define B_SZ   16
#define V_IN   1024
#define V_OUT  4096
#define C_IN   128
#define C_OUT  256
#define K_NB   18
#define NNZ    16384
#define K_GEMM (K_NB * C_IN)   // 2304
#define BK     64
#define NKT    (K_GEMM / BK)   // 36

typedef __attribute__((ext_vector_type(8))) short bf16x8;   // 8 bf16 = 4 VGPRs
typedef __attribute__((ext_vector_type(4))) float f32x4;

#define GLOAD16(src, dst) __builtin_amdgcn_global_load_lds( \
    (const __attribute__((address_space(1))) unsigned int*)(src), \
    (__attribute__((address_space(3))) unsigned int*)(dst), 16, 0, 0)

#define MFMA16(a_, b_, c_) __builtin_amdgcn_mfma_f32_16x16x32_bf16((a_), (b_), (c_), 0, 0, 0)

// ---------------- fused hist + combined-weight kernel ----------------
// blocks 0..63: histogram of rows into counts
// blocks 64..207: weight K-tile quadrant images (blk-64 = kt*4+part)
// block 208: bias fold
__global__ __launch_bounds__(256) void hist_wcomb_kernel(
    const int* __restrict__ rows, int* __restrict__ counts,
    const float* __restrict__ W1, const float* __restrict__ Wd3,
    const float* __restrict__ W2d3, const float* __restrict__ Wf,
    const float* __restrict__ b1, const float* __restrict__ bd3,
    const float* __restrict__ b2d3, const float* __restrict__ bf,
    __hip_bfloat16* __restrict__ wTs, float* __restrict__ bias) {
    const int t = threadIdx.x;
    if (blockIdx.x < 64) {                    // histogram part
        int n = blockIdx.x * 256 + t;
        atomicAdd(&counts[rows[n]], 1);
        return;
    }
    const int blk = blockIdx.x - 64;
    if (blk == NKT * 4) {                     // bias block
        float v = b1[t];
        if (t < 128)      v += bf[t];
        else if (t < 192) v += b2d3[t - 128];
        else              v += bd3[t - 192];
        bias[t] = v;
        return;
    }
    const int kt = blk >> 2, part = blk & 3;
    __shared__ __hip_bfloat16 img[4096];     // 64 cols x 64 k
    const int k0 = kt * 64;

    auto put = [&](int cl, int col7, int kl, float v) {
        int kb    = (kl >> 3) << 4;
        int kslot = kb ^ (col7 << 4);
        int idx   = (((cl << 3) | (kslot >> 4)) << 3) | (kl & 7);
        img[idx] = __float2bfloat16(v);
    };

    if (part < 2) {
        const int cbase = part << 6;                 // cols 0..63 or 64..127 (Wf)
        for (int i = t; i < 4096; i += 256) {
            int kl = i >> 6, cl = i & 63;
            int col = cbase + cl, r = k0 + kl;
            float v = Wf[r * 128 + col];
            if (r < 128) v += W1[r * 256 + col];
            put(cl, col & 7, kl, v);
        }
    } else if (part == 2) {                          // cols 128..191 (W2d3, r<1536)
        for (int i = t; i < 4096; i += 256) {
            int kl = i >> 6, cl = i & 63;
            int r = k0 + kl;
            float v = (r < 1536) ? W2d3[r * 64 + cl] : 0.f;
            if (r < 128) v += W1[r * 256 + 128 + cl];
            put(cl, cl & 7, kl, v);
        }
    } else {                                         // cols 192..255 (Wd3, r<768)
        for (int i = t; i < 4096; i += 256) {
            int kl = i >> 6, cl = i & 63;
            int r = k0 + kl;
            float v = (r < 768) ? Wd3[r * 64 + cl] : 0.f;
            if (r < 128) v += W1[r * 256 + 192 + cl];
            put(cl, cl & 7, kl, v);
        }
    }
    __syncthreads();
    // linear dump: 8 KB quadrant
    ulonglong2* dst = (ulonglong2*)(wTs + (size_t)kt * 16384 + part * 4096);
    const ulonglong2* srcv = (const ulonglong2*)img;
#pragma unroll
    for (int i = t; i < 512; i += 256) dst[i] = srcv[i];
}

// 1024 threads, shfl-based scan of 4096 counts (4 per thread), 1 barrier
__global__ void scan_kernel(const int* __restrict__ counts, int* offsets, int* cursor) {
    __shared__ int wsum[16];
    int t = threadIdx.x;
    int lane = t & 63, wid = t >> 6;
    int base4 = t * 4;
    int c0 = counts[base4], c1 = counts[base4 + 1], c2 = counts[base4 + 2], c3 = counts[base4 + 3];
    int tot = c0 + c1 + c2 + c3;
    int v = tot;
#pragma unroll
    for (int d = 1; d < 64; d <<= 1) {
        int u = __shfl_up(v, d);
        if (lane >= d) v += u;
    }
    if (lane == 63) wsum[wid] = v;
    __syncthreads();
    int wbase = 0;
#pragma unroll
    for (int w = 0; w < 16; ++w) wbase += (w < wid) ? wsum[w] : 0;
    int incl = wbase + v;
    int excl = incl - tot;
    offsets[base4]     = excl;
    offsets[base4 + 1] = excl + c0;
    offsets[base4 + 2] = excl + c0 + c1;
    offsets[base4 + 3] = excl + c0 + c1 + c2;
    cursor[base4]     = excl;
    cursor[base4 + 1] = excl + c0;
    cursor[base4 + 2] = excl + c0 + c1;
    cursor[base4 + 3] = excl + c0 + c1 + c2;
    if (t == 1023) offsets[V_OUT] = incl;
}

// fill: scatter packed (col,val) pairs in CSR order
__global__ void fill_kernel(const int* __restrict__ rows, const int* __restrict__ cols,
                            const float* __restrict__ vals, int* cursor,
                            float2* __restrict__ pcv) {
    int n = blockIdx.x * blockDim.x + threadIdx.x;
    if (n < NNZ) {
        int r = rows[n];
        int pos = atomicAdd(&cursor[r], 1);
        pcv[pos] = make_float2(__int_as_float(cols[n]), vals[n]);
    }
}

// ---------------- pooling: block = out-row, threads = (batch 16) x (c4 32),
// packed (col,val) CSR stream + float4 x loads ----------------
__global__ __launch_bounds__(512) void pool_kernel(
    const float* __restrict__ x, const int* __restrict__ offsets,
    const float2* __restrict__ pcv, __hip_bfloat16* __restrict__ pool) {
    int r = blockIdx.x;
    int t = threadIdx.x;
    int b = t >> 5, c4 = t & 31;
    int j0 = offsets[r], j1 = offsets[r + 1];
    const float4* xb = (const float4*)x + (size_t)b * (V_IN * 32);
    float4 acc = {0.f, 0.f, 0.f, 0.f};
    for (int j = j0; j < j1; ++j) {
        float2 cv = pcv[j];
        int col = __float_as_int(cv.x);
        float v = cv.y;
        float4 xv = xb[col * 32 + c4];
        acc.x += v * xv.x; acc.y += v * xv.y; acc.z += v * xv.z; acc.w += v * xv.w;
    }
    ushort4 o;
    o.x = __builtin_bit_cast(unsigned short, __float2bfloat16(acc.x));
    o.y = __builtin_bit_cast(unsigned short, __float2bfloat16(acc.y));
    o.z = __builtin_bit_cast(unsigned short, __float2bfloat16(acc.z));
    o.w = __builtin_bit_cast(unsigned short, __float2bfloat16(acc.w));
    ((ushort4*)pool)[((size_t)b * V_OUT + r) * 32 + c4] = o;
}

// ---------------- gathered GEMM: 256x256 tile, 16 waves, balanced K-skip (round-5 verbatim) ----------------
__global__ __launch_bounds__(1024, 4) void gemm_kernel(
    const __hip_bfloat16* __restrict__ pool,    // [16][4096][128] bf16
    const __hip_bfloat16* __restrict__ wTs,     // [36][16384] bf16, pre-swizzled K-tile images
    const float* __restrict__ bias,             // [256]
    const int* __restrict__ spiral,             // [4096][18]
    float* __restrict__ out)                    // [16][4096][256] f32
{
    // LDS: A slots @0,32768 ; B slots @65536,98304 ; spiral cache @131072 (18432B)
    __shared__ __align__(16) char smem[149504];
    int* spl = (int*)(smem + 131072);

    const int tid  = threadIdx.x;
    const int lane = tid & 63;
    const int wid  = tid >> 6;          // 0..15
    const int wc   = wid & 3;
    const int wm   = (wid >> 2) << 6;   // 0,64,128,192

    const int bid = blockIdx.x;
    const int bm  = ((bid & 7) << 5) + (bid >> 3);   // bijective XCD swizzle (256 = 8*32)
    const int b   = bm >> 4;                          // batch
    const int v0  = (bm & 15) << 8;                   // m-tile origin within batch

    // cache this block's spiral rows in LDS: 256 rows x 18
    for (int i = tid; i < 256 * K_NB; i += 1024) spl[i] = spiral[v0 * K_NB + i];
    asm volatile("s_waitcnt vmcnt(0) lgkmcnt(0)" ::: "memory");
    __builtin_amdgcn_s_barrier();

    const char* poolBytes = (const char*)(pool + (size_t)b * V_OUT * C_IN);
    const char* wTsBytes  = (const char*)wTs;
    // inverse-swizzled source column byte (identical for both 1024-chunks)
    const int sb = ((tid & 7) << 4) ^ (((tid >> 3) & 7) << 4);

    auto stageA = [&](int kt) {          // 2 vmem loads
        const int j   = kt >> 1;
        const int c0b = (kt & 1) << 7;
        char* dst = smem + ((kt & 1) << 15);
#pragma unroll
        for (int ch = 0; ch < 2; ++ch) {
            int flat = (ch << 10) + tid;
            int sidx = spl[(flat >> 3) * K_NB + j];
            GLOAD16(poolBytes + ((size_t)sidx << 8) + (c0b + sb), dst + flat * 16);
        }
    };
    auto stageB = [&](int kt) {          // 2 vmem loads
        const char* src = wTsBytes + ((size_t)kt << 15);
        char* dst = smem + 65536 + ((kt & 1) << 15);
#pragma unroll
        for (int ch = 0; ch < 2; ++ch) {
            int off = ((ch << 10) + tid) << 4;
            GLOAD16(src + off, dst + off);
        }
    };

    // per-lane fragment-read constants
    const int l15   = lane & 15;
    const int swm   = (lane & 7) << 4;          // frag-row&7 == lane&7
    const int klane = (lane >> 4) << 4;         // 0,16,32,48 (byte)
    const int aBase = (wm + l15) << 7;
    const int bOff0 = (((2 * wc)     << 4) + l15) << 7;   // full tile 0
    const int bOff1 = (((2 * wc + 1) << 4) + l15) << 7;   // full tile 1
    const int bOff2 = (((8 + wc)     << 4) + l15) << 7;   // mid tile
    const int bOff3 = (((12 + wc)    << 4) + l15) << 7;   // short tile

    f32x4 acc[4][4] = {};

    stageA(0);
    stageB(0);

    for (int kt = 0; kt < NKT; ++kt) {
        const int s = kt & 1;
        const char* As = smem + (s << 15);
        const char* Bs = smem + 65536 + (s << 15);

        if (kt + 1 < NKT) {
            stageA(kt + 1);
            asm volatile("s_waitcnt vmcnt(2)" ::: "memory");   // A(kt),B(kt) landed
        } else {
            asm volatile("s_waitcnt vmcnt(0)" ::: "memory");
        }
        __builtin_amdgcn_s_barrier();
        __builtin_amdgcn_sched_barrier(0);

        const bool doMid   = kt < 24;
        const bool doShort = kt < 12;

#pragma unroll
        for (int ks = 0; ks < 2; ++ks) {
            const int kk = (ks * 64 + klane) ^ swm;
            bf16x8 a0 = *(const bf16x8*)(As + aBase + (0 << 11) + kk);
            bf16x8 a1 = *(const bf16x8*)(As + aBase + (1 << 11) + kk);
            bf16x8 a2 = *(const bf16x8*)(As + aBase + (2 << 11) + kk);
            bf16x8 a3 = *(const bf16x8*)(As + aBase + (3 << 11) + kk);
            bf16x8 bb0 = *(const bf16x8*)(Bs + bOff0 + kk);
            bf16x8 bb1 = *(const bf16x8*)(Bs + bOff1 + kk);
            __builtin_amdgcn_s_setprio(1);
            acc[0][0] = MFMA16(a0, bb0, acc[0][0]);
            acc[1][0] = MFMA16(a1, bb0, acc[1][0]);
            acc[2][0] = MFMA16(a2, bb0, acc[2][0]);
            acc[3][0] = MFMA16(a3, bb0, acc[3][0]);
            acc[0][1] = MFMA16(a0, bb1, acc[0][1]);
            acc[1][1] = MFMA16(a1, bb1, acc[1][1]);
            acc[2][1] = MFMA16(a2, bb1, acc[2][1]);
            acc[3][1] = MFMA16(a3, bb1, acc[3][1]);
            __builtin_amdgcn_s_setprio(0);
            if (doMid) {
                bf16x8 bb2 = *(const bf16x8*)(Bs + bOff2 + kk);
                __builtin_amdgcn_s_setprio(1);
                acc[0][2] = MFMA16(a0, bb2, acc[0][2]);
                acc[1][2] = MFMA16(a1, bb2, acc[1][2]);
                acc[2][2] = MFMA16(a2, bb2, acc[2][2]);
                acc[3][2] = MFMA16(a3, bb2, acc[3][2]);
                __builtin_amdgcn_s_setprio(0);
            }
            if (doShort) {
                bf16x8 bb3 = *(const bf16x8*)(Bs + bOff3 + kk);
                __builtin_amdgcn_s_setprio(1);
                acc[0][3] = MFMA16(a0, bb3, acc[0][3]);
                acc[1][3] = MFMA16(a1, bb3, acc[1][3]);
                acc[2][3] = MFMA16(a2, bb3, acc[2][3]);
                acc[3][3] = MFMA16(a3, bb3, acc[3][3]);
                __builtin_amdgcn_s_setprio(0);
            }
            if (ks == 0 && kt + 1 < NKT) stageB(kt + 1);
        }

        __builtin_amdgcn_s_barrier();        // end of K-tile: slot reads complete
        __builtin_amdgcn_sched_barrier(0);
    }

    // epilogue: +bias, relu, store f32
    const int nt[4] = {2 * wc, 2 * wc + 1, 8 + wc, 12 + wc};
#pragma unroll
    for (int ni = 0; ni < 4; ++ni) {
        int col = (nt[ni] << 4) + l15;
        float bz = bias[col];
#pragma unroll
        for (int mi = 0; mi < 4; ++mi) {
            int row0 = v0 + wm + mi * 16 + ((lane >> 4) << 2);
#pragma unroll
            for (int r4 = 0; r4 < 4; ++r4) {
                float v = acc[mi][ni][r4] + bz;
                out[((size_t)(b * V_OUT + row0 + r4)) * C_OUT + col] = v > 0.f ? v : 0.f;
            }
        }
    }
}

extern "C" void kernel_launch(void* const* d_in, const int* in_sizes, int n_in,
                              void* d_out, int out_size, void* d_ws, size_t ws_size,
                              hipStream_t stream) {
    const float* x     = (const float*)d_in[0];
    const float* vals  = (const float*)d_in[1];
    const float* W1    = (const float*)d_in[2];
    const float* b1    = (const float*)d_in[3];
    const float* Wd3   = (const float*)d_in[4];
    const float* bd3   = (const float*)d_in[5];
    const float* W2d3  = (const float*)d_in[6];
    const float* b2d3  = (const float*)d_in[7];
    const float* Wf    = (const float*)d_in[8];
    const float* bf    = (const float*)d_in[9];
    const int*   rows  = (const int*)d_in[10];
    const int*   cols  = (const int*)d_in[11];
    const int*   spiral= (const int*)d_in[12];
    float* out = (float*)d_out;

    // workspace layout
    char* ws = (char*)d_ws;
    __hip_bfloat16* pool = (__hip_bfloat16*)ws;                              // 16,777,216 B
    __hip_bfloat16* wTs  = (__hip_bfloat16*)(ws + 16777216);                 //  1,179,648 B
    float* bias          = (float*)(ws + 16777216 + 1179648);                //      1,024 B
    int*   counts        = (int*)(ws + 16777216 + 1179648 + 1024);
    int*   offsets       = counts + V_OUT;          // V_OUT+1 ints
    int*   cursor        = offsets + V_OUT + 4;     // padded
    float2* pcv          = (float2*)(cursor + V_OUT);  // NNZ float2 (8B-aligned)

    hipMemsetAsync(counts, 0, V_OUT * sizeof(int), stream);
    hist_wcomb_kernel<<<64 + NKT * 4 + 1, 256, 0, stream>>>(
        rows, counts, W1, Wd3, W2d3, Wf, b1, bd3, b2d3, bf, wTs, bias);
    scan_kernel<<<1, 1024, 0, stream>>>(counts, offsets, cursor);
    fill_kernel<<<NNZ / 256, 256, 0, stream>>>(rows, cols, vals, cursor, pcv);
    pool_kernel<<<V_OUT, 512, 0, stream>>>(x, offsets, pcv, pool);
    gemm_kernel<<<256, 1024, 0, stream>>>(pool, wTs, bias, spiral, out);
}

// Round 16
// 101.652 us; speedup vs baseline: 1.0604x; 1.0198x over previous
//
#include <hip/hip_runtime.h>
#include <hip/hip_bf16.h>

// Problem constants
#define B_SZ   16
#define V_IN   1024
#define V_OUT  4096
#define C_IN   128
#define C_OUT  256
#define K_NB   18
#define NNZ    16384
#define K_GEMM (K_NB * C_IN)   // 2304
#define BK     64
#define NKT    (K_GEMM / BK)   // 36

typedef __attribute__((ext_vector_type(8))) short bf16x8;   // 8 bf16 = 4 VGPRs
typedef __attribute__((ext_vector_type(4))) float f32x4;

#define GLOAD16(src, dst) __builtin_amdgcn_global_load_lds( \
    (const __attribute__((address_space(1))) unsigned int*)(src), \
    (__attribute__((address_space(3))) unsigned int*)(dst), 16, 0, 0)

#define MFMA16(a_, b_, c_) __builtin_amdgcn_mfma_f32_16x16x32_bf16((a_), (b_), (c_), 0, 0, 0)

// ---------------- fused hist + combined-weight kernel ----------------
// blocks 0..63: histogram of rows into counts
// blocks 64..207: weight K-tile quadrant images (blk-64 = kt*4+part)
// block 208: bias fold
__global__ __launch_bounds__(256) void hist_wcomb_kernel(
    const int* __restrict__ rows, int* __restrict__ counts,
    const float* __restrict__ W1, const float* __restrict__ Wd3,
    const float* __restrict__ W2d3, const float* __restrict__ Wf,
    const float* __restrict__ b1, const float* __restrict__ bd3,
    const float* __restrict__ b2d3, const float* __restrict__ bf,
    __hip_bfloat16* __restrict__ wTs, float* __restrict__ bias) {
    const int t = threadIdx.x;
    if (blockIdx.x < 64) {                    // histogram part
        int n = blockIdx.x * 256 + t;
        atomicAdd(&counts[rows[n]], 1);
        return;
    }
    const int blk = blockIdx.x - 64;
    if (blk == NKT * 4) {                     // bias block
        float v = b1[t];
        if (t < 128)      v += bf[t];
        else if (t < 192) v += b2d3[t - 128];
        else              v += bd3[t - 192];
        bias[t] = v;
        return;
    }
    const int kt = blk >> 2, part = blk & 3;
    __shared__ __hip_bfloat16 img[4096];     // 64 cols x 64 k
    const int k0 = kt * 64;

    auto put = [&](int cl, int col7, int kl, float v) {
        int kb    = (kl >> 3) << 4;
        int kslot = kb ^ (col7 << 4);
        int idx   = (((cl << 3) | (kslot >> 4)) << 3) | (kl & 7);
        img[idx] = __float2bfloat16(v);
    };

    if (part < 2) {
        const int cbase = part << 6;                 // cols 0..63 or 64..127 (Wf)
        for (int i = t; i < 4096; i += 256) {
            int kl = i >> 6, cl = i & 63;
            int col = cbase + cl, r = k0 + kl;
            float v = Wf[r * 128 + col];
            if (r < 128) v += W1[r * 256 + col];
            put(cl, col & 7, kl, v);
        }
    } else if (part == 2) {                          // cols 128..191 (W2d3, r<1536)
        for (int i = t; i < 4096; i += 256) {
            int kl = i >> 6, cl = i & 63;
            int r = k0 + kl;
            float v = (r < 1536) ? W2d3[r * 64 + cl] : 0.f;
            if (r < 128) v += W1[r * 256 + 128 + cl];
            put(cl, cl & 7, kl, v);
        }
    } else {                                         // cols 192..255 (Wd3, r<768)
        for (int i = t; i < 4096; i += 256) {
            int kl = i >> 6, cl = i & 63;
            int r = k0 + kl;
            float v = (r < 768) ? Wd3[r * 64 + cl] : 0.f;
            if (r < 128) v += W1[r * 256 + 192 + cl];
            put(cl, cl & 7, kl, v);
        }
    }
    __syncthreads();
    // linear dump: 8 KB quadrant
    ulonglong2* dst = (ulonglong2*)(wTs + (size_t)kt * 16384 + part * 4096);
    const ulonglong2* srcv = (const ulonglong2*)img;
#pragma unroll
    for (int i = t; i < 512; i += 256) dst[i] = srcv[i];
}

// 1024 threads, shfl-based scan of 4096 counts (4 per thread), 1 barrier
__global__ void scan_kernel(const int* __restrict__ counts, int* offsets, int* cursor) {
    __shared__ int wsum[16];
    int t = threadIdx.x;
    int lane = t & 63, wid = t >> 6;
    int base4 = t * 4;
    int c0 = counts[base4], c1 = counts[base4 + 1], c2 = counts[base4 + 2], c3 = counts[base4 + 3];
    int tot = c0 + c1 + c2 + c3;
    int v = tot;
#pragma unroll
    for (int d = 1; d < 64; d <<= 1) {
        int u = __shfl_up(v, d);
        if (lane >= d) v += u;
    }
    if (lane == 63) wsum[wid] = v;
    __syncthreads();
    int wbase = 0;
#pragma unroll
    for (int w = 0; w < 16; ++w) wbase += (w < wid) ? wsum[w] : 0;
    int incl = wbase + v;
    int excl = incl - tot;
    offsets[base4]     = excl;
    offsets[base4 + 1] = excl + c0;
    offsets[base4 + 2] = excl + c0 + c1;
    offsets[base4 + 3] = excl + c0 + c1 + c2;
    cursor[base4]     = excl;
    cursor[base4 + 1] = excl + c0;
    cursor[base4 + 2] = excl + c0 + c1;
    cursor[base4 + 3] = excl + c0 + c1 + c2;
    if (t == 1023) offsets[V_OUT] = incl;
}

// fill: scatter packed (col,val) pairs in CSR order
__global__ void fill_kernel(const int* __restrict__ rows, const int* __restrict__ cols,
                            const float* __restrict__ vals, int* cursor,
                            float2* __restrict__ pcv) {
    int n = blockIdx.x * blockDim.x + threadIdx.x;
    if (n < NNZ) {
        int r = rows[n];
        int pos = atomicAdd(&cursor[r], 1);
        pcv[pos] = make_float2(__int_as_float(cols[n]), vals[n]);
    }
}

// ---------------- pooling: block = out-row, threads = (batch 16) x (c4 32),
// packed (col,val) CSR stream + float4 x loads ----------------
__global__ __launch_bounds__(512) void pool_kernel(
    const float* __restrict__ x, const int* __restrict__ offsets,
    const float2* __restrict__ pcv, __hip_bfloat16* __restrict__ pool) {
    int r = blockIdx.x;
    int t = threadIdx.x;
    int b = t >> 5, c4 = t & 31;
    int j0 = offsets[r], j1 = offsets[r + 1];
    const float4* xb = (const float4*)x + (size_t)b * (V_IN * 32);
    float4 acc = {0.f, 0.f, 0.f, 0.f};
    for (int j = j0; j < j1; ++j) {
        float2 cv = pcv[j];
        int col = __float_as_int(cv.x);
        float v = cv.y;
        float4 xv = xb[col * 32 + c4];
        acc.x += v * xv.x; acc.y += v * xv.y; acc.z += v * xv.z; acc.w += v * xv.w;
    }
    ushort4 o;
    o.x = __builtin_bit_cast(unsigned short, __float2bfloat16(acc.x));
    o.y = __builtin_bit_cast(unsigned short, __float2bfloat16(acc.y));
    o.z = __builtin_bit_cast(unsigned short, __float2bfloat16(acc.z));
    o.w = __builtin_bit_cast(unsigned short, __float2bfloat16(acc.w));
    ((ushort4*)pool)[((size_t)b * V_OUT + r) * 32 + c4] = o;
}

// ---------------- gathered GEMM: 256x256 tile, 16 waves, balanced K-skip,
// SINGLE barrier per K-tile (stageA moved after the barrier; slot-overwrite provably safe) ----------------
__global__ __launch_bounds__(1024, 4) void gemm_kernel(
    const __hip_bfloat16* __restrict__ pool,    // [16][4096][128] bf16
    const __hip_bfloat16* __restrict__ wTs,     // [36][16384] bf16, pre-swizzled K-tile images
    const float* __restrict__ bias,             // [256]
    const int* __restrict__ spiral,             // [4096][18]
    float* __restrict__ out)                    // [16][4096][256] f32
{
    // LDS: A slots @0,32768 ; B slots @65536,98304 ; spiral cache @131072 (18432B)
    __shared__ __align__(16) char smem[149504];
    int* spl = (int*)(smem + 131072);

    const int tid  = threadIdx.x;
    const int lane = tid & 63;
    const int wid  = tid >> 6;          // 0..15
    const int wc   = wid & 3;
    const int wm   = (wid >> 2) << 6;   // 0,64,128,192

    const int bid = blockIdx.x;
    const int bm  = ((bid & 7) << 5) + (bid >> 3);   // bijective XCD swizzle (256 = 8*32)
    const int b   = bm >> 4;                          // batch
    const int v0  = (bm & 15) << 8;                   // m-tile origin within batch

    // cache this block's spiral rows in LDS: 256 rows x 18
    for (int i = tid; i < 256 * K_NB; i += 1024) spl[i] = spiral[v0 * K_NB + i];
    asm volatile("s_waitcnt vmcnt(0) lgkmcnt(0)" ::: "memory");
    __builtin_amdgcn_s_barrier();

    const char* poolBytes = (const char*)(pool + (size_t)b * V_OUT * C_IN);
    const char* wTsBytes  = (const char*)wTs;
    // inverse-swizzled source column byte (identical for both 1024-chunks)
    const int sb = ((tid & 7) << 4) ^ (((tid >> 3) & 7) << 4);

    auto stageA = [&](int kt) {          // 2 vmem loads
        const int j   = kt >> 1;
        const int c0b = (kt & 1) << 7;
        char* dst = smem + ((kt & 1) << 15);
#pragma unroll
        for (int ch = 0; ch < 2; ++ch) {
            int flat = (ch << 10) + tid;
            int sidx = spl[(flat >> 3) * K_NB + j];
            GLOAD16(poolBytes + ((size_t)sidx << 8) + (c0b + sb), dst + flat * 16);
        }
    };
    auto stageB = [&](int kt) {          // 2 vmem loads
        const char* src = wTsBytes + ((size_t)kt << 15);
        char* dst = smem + 65536 + ((kt & 1) << 15);
#pragma unroll
        for (int ch = 0; ch < 2; ++ch) {
            int off = ((ch << 10) + tid) << 4;
            GLOAD16(src + off, dst + off);
        }
    };

    // per-lane fragment-read constants
    const int l15   = lane & 15;
    const int swm   = (lane & 7) << 4;          // frag-row&7 == lane&7
    const int klane = (lane >> 4) << 4;         // 0,16,32,48 (byte)
    const int aBase = (wm + l15) << 7;
    const int bOff0 = (((2 * wc)     << 4) + l15) << 7;   // full tile 0
    const int bOff1 = (((2 * wc + 1) << 4) + l15) << 7;   // full tile 1
    const int bOff2 = (((8 + wc)     << 4) + l15) << 7;   // mid tile
    const int bOff3 = (((12 + wc)    << 4) + l15) << 7;   // short tile

    f32x4 acc[4][4] = {};

    stageA(0);
    stageB(0);

    for (int kt = 0; kt < NKT; ++kt) {
        const int s = kt & 1;
        const char* As = smem + (s << 15);
        const char* Bs = smem + 65536 + (s << 15);

        // A(kt),B(kt) were issued >= half a tile ago -> this drain is nearly free.
        asm volatile("s_waitcnt vmcnt(0)" ::: "memory");
        __builtin_amdgcn_s_barrier();            // single barrier per K-tile
        __builtin_amdgcn_sched_barrier(0);

        // safe to overwrite slot (kt+1)&1 now: all waves are past the barrier,
        // so all tile-(kt-1) reads of that slot are complete.
        if (kt + 1 < NKT) stageA(kt + 1);

        const bool doMid   = kt < 24;
        const bool doShort = kt < 12;

#pragma unroll
        for (int ks = 0; ks < 2; ++ks) {
            const int kk = (ks * 64 + klane) ^ swm;
            bf16x8 a0 = *(const bf16x8*)(As + aBase + (0 << 11) + kk);
            bf16x8 a1 = *(const bf16x8*)(As + aBase + (1 << 11) + kk);
            bf16x8 a2 = *(const bf16x8*)(As + aBase + (2 << 11) + kk);
            bf16x8 a3 = *(const bf16x8*)(As + aBase + (3 << 11) + kk);
            bf16x8 bb0 = *(const bf16x8*)(Bs + bOff0 + kk);
            bf16x8 bb1 = *(const bf16x8*)(Bs + bOff1 + kk);
            __builtin_amdgcn_s_setprio(1);
            acc[0][0] = MFMA16(a0, bb0, acc[0][0]);
            acc[1][0] = MFMA16(a1, bb0, acc[1][0]);
            acc[2][0] = MFMA16(a2, bb0, acc[2][0]);
            acc[3][0] = MFMA16(a3, bb0, acc[3][0]);
            acc[0][1] = MFMA16(a0, bb1, acc[0][1]);
            acc[1][1] = MFMA16(a1, bb1, acc[1][1]);
            acc[2][1] = MFMA16(a2, bb1, acc[2][1]);
            acc[3][1] = MFMA16(a3, bb1, acc[3][1]);
            __builtin_amdgcn_s_setprio(0);
            if (doMid) {
                bf16x8 bb2 = *(const bf16x8*)(Bs + bOff2 + kk);
                __builtin_amdgcn_s_setprio(1);
                acc[0][2] = MFMA16(a0, bb2, acc[0][2]);
                acc[1][2] = MFMA16(a1, bb2, acc[1][2]);
                acc[2][2] = MFMA16(a2, bb2, acc[2][2]);
                acc[3][2] = MFMA16(a3, bb2, acc[3][2]);
                __builtin_amdgcn_s_setprio(0);
            }
            if (doShort) {
                bf16x8 bb3 = *(const bf16x8*)(Bs + bOff3 + kk);
                __builtin_amdgcn_s_setprio(1);
                acc[0][3] = MFMA16(a0, bb3, acc[0][3]);
                acc[1][3] = MFMA16(a1, bb3, acc[1][3]);
                acc[2][3] = MFMA16(a2, bb3, acc[2][3]);
                acc[3][3] = MFMA16(a3, bb3, acc[3][3]);
                __builtin_amdgcn_s_setprio(0);
            }
            if (ks == 0 && kt + 1 < NKT) stageB(kt + 1);
        }
        // no end-of-tile barrier: next tile's top barrier provides the ordering
    }

    // epilogue: +bias, relu, store f32
    const int nt[4] = {2 * wc, 2 * wc + 1, 8 + wc, 12 + wc};
#pragma unroll
    for (int ni = 0; ni < 4; ++ni) {
        int col = (nt[ni] << 4) + l15;
        float bz = bias[col];
#pragma unroll
        for (int mi = 0; mi < 4; ++mi) {
            int row0 = v0 + wm + mi * 16 + ((lane >> 4) << 2);
#pragma unroll
            for (int r4 = 0; r4 < 4; ++r4) {
                float v = acc[mi][ni][r4] + bz;
                out[((size_t)(b * V_OUT + row0 + r4)) * C_OUT + col] = v > 0.f ? v : 0.f;
            }
        }
    }
}

extern "C" void kernel_launch(void* const* d_in, const int* in_sizes, int n_in,
                              void* d_out, int out_size, void* d_ws, size_t ws_size,
                              hipStream_t stream) {
    const float* x     = (const float*)d_in[0];
    const float* vals  = (const float*)d_in[1];
    const float* W1    = (const float*)d_in[2];
    const float* b1    = (const float*)d_in[3];
    const float* Wd3   = (const float*)d_in[4];
    const float* bd3   = (const float*)d_in[5];
    const float* W2d3  = (const float*)d_in[6];
    const float* b2d3  = (const float*)d_in[7];
    const float* Wf    = (const float*)d_in[8];
    const float* bf    = (const float*)d_in[9];
    const int*   rows  = (const int*)d_in[10];
    const int*   cols  = (const int*)d_in[11];
    const int*   spiral= (const int*)d_in[12];
    float* out = (float*)d_out;

    // workspace layout
    char* ws = (char*)d_ws;
    __hip_bfloat16* pool = (__hip_bfloat16*)ws;                              // 16,777,216 B
    __hip_bfloat16* wTs  = (__hip_bfloat16*)(ws + 16777216);                 //  1,179,648 B
    float* bias          = (float*)(ws + 16777216 + 1179648);                //      1,024 B
    int*   counts        = (int*)(ws + 16777216 + 1179648 + 1024);
    int*   offsets       = counts + V_OUT;          // V_OUT+1 ints
    int*   cursor        = offsets + V_OUT + 4;     // padded
    float2* pcv          = (float2*)(cursor + V_OUT);  // NNZ float2 (8B-aligned)

    hipMemsetAsync(counts, 0, V_OUT * sizeof(int), stream);
    hist_wcomb_kernel<<<64 + NKT * 4 + 1, 256, 0, stream>>>(
        rows, counts, W1, Wd3, W2d3, Wf, b1, bd3, b2d3, bf, wTs, bias);
    scan_kernel<<<1, 1024, 0, stream>>>(counts, offsets, cursor);
    fill_kernel<<<NNZ / 256, 256, 0, stream>>>(rows, cols, vals, cursor, pcv);
    pool_kernel<<<V_OUT, 512, 0, stream>>>(x, offsets, pcv, pool);
    gemm_kernel<<<256, 1024, 0, stream>>>(pool, wTs, bias, spiral, out);
}

// Round 17
// 101.364 us; speedup vs baseline: 1.0634x; 1.0028x over previous
//
#include <hip/hip_runtime.h>
#include <hip/hip_bf16.h>

// Problem constants
#define B_SZ   16
#define V_IN   1024
#define V_OUT  4096
#define C_IN   128
#define C_OUT  256
#define K_NB   18
#define NNZ    16384
#define K_GEMM (K_NB * C_IN)   // 2304
#define BK     64
#define NKT    (K_GEMM / BK)   // 36

typedef __attribute__((ext_vector_type(8))) short bf16x8;   // 8 bf16 = 4 VGPRs
typedef __attribute__((ext_vector_type(4))) float f32x4;

#define GLOAD16(src, dst) __builtin_amdgcn_global_load_lds( \
    (const __attribute__((address_space(1))) unsigned int*)(src), \
    (__attribute__((address_space(3))) unsigned int*)(dst), 16, 0, 0)

#define MFMA16(a_, b_, c_) __builtin_amdgcn_mfma_f32_16x16x32_bf16((a_), (b_), (c_), 0, 0, 0)

// ---------------- fused hist + combined-weight kernel ----------------
// blocks 0..63: histogram of rows into counts
// blocks 64..207: weight K-tile quadrant images (blk-64 = kt*4+part)
// block 208: bias fold
__global__ __launch_bounds__(256) void hist_wcomb_kernel(
    const int* __restrict__ rows, int* __restrict__ counts,
    const float* __restrict__ W1, const float* __restrict__ Wd3,
    const float* __restrict__ W2d3, const float* __restrict__ Wf,
    const float* __restrict__ b1, const float* __restrict__ bd3,
    const float* __restrict__ b2d3, const float* __restrict__ bf,
    __hip_bfloat16* __restrict__ wTs, float* __restrict__ bias) {
    const int t = threadIdx.x;
    if (blockIdx.x < 64) {                    // histogram part
        int n = blockIdx.x * 256 + t;
        atomicAdd(&counts[rows[n]], 1);
        return;
    }
    const int blk = blockIdx.x - 64;
    if (blk == NKT * 4) {                     // bias block
        float v = b1[t];
        if (t < 128)      v += bf[t];
        else if (t < 192) v += b2d3[t - 128];
        else              v += bd3[t - 192];
        bias[t] = v;
        return;
    }
    const int kt = blk >> 2, part = blk & 3;
    __shared__ __hip_bfloat16 img[4096];     // 64 cols x 64 k
    const int k0 = kt * 64;

    auto put = [&](int cl, int col7, int kl, float v) {
        int kb    = (kl >> 3) << 4;
        int kslot = kb ^ (col7 << 4);
        int idx   = (((cl << 3) | (kslot >> 4)) << 3) | (kl & 7);
        img[idx] = __float2bfloat16(v);
    };

    if (part < 2) {
        const int cbase = part << 6;                 // cols 0..63 or 64..127 (Wf)
        for (int i = t; i < 4096; i += 256) {
            int kl = i >> 6, cl = i & 63;
            int col = cbase + cl, r = k0 + kl;
            float v = Wf[r * 128 + col];
            if (r < 128) v += W1[r * 256 + col];
            put(cl, col & 7, kl, v);
        }
    } else if (part == 2) {                          // cols 128..191 (W2d3, r<1536)
        for (int i = t; i < 4096; i += 256) {
            int kl = i >> 6, cl = i & 63;
            int r = k0 + kl;
            float v = (r < 1536) ? W2d3[r * 64 + cl] : 0.f;
            if (r < 128) v += W1[r * 256 + 128 + cl];
            put(cl, cl & 7, kl, v);
        }
    } else {                                         // cols 192..255 (Wd3, r<768)
        for (int i = t; i < 4096; i += 256) {
            int kl = i >> 6, cl = i & 63;
            int r = k0 + kl;
            float v = (r < 768) ? Wd3[r * 64 + cl] : 0.f;
            if (r < 128) v += W1[r * 256 + 192 + cl];
            put(cl, cl & 7, kl, v);
        }
    }
    __syncthreads();
    // linear dump: 8 KB quadrant
    ulonglong2* dst = (ulonglong2*)(wTs + (size_t)kt * 16384 + part * 4096);
    const ulonglong2* srcv = (const ulonglong2*)img;
#pragma unroll
    for (int i = t; i < 512; i += 256) dst[i] = srcv[i];
}

// 1024 threads, shfl-based scan of 4096 counts (4 per thread), 1 barrier
__global__ void scan_kernel(const int* __restrict__ counts, int* offsets, int* cursor) {
    __shared__ int wsum[16];
    int t = threadIdx.x;
    int lane = t & 63, wid = t >> 6;
    int base4 = t * 4;
    int c0 = counts[base4], c1 = counts[base4 + 1], c2 = counts[base4 + 2], c3 = counts[base4 + 3];
    int tot = c0 + c1 + c2 + c3;
    int v = tot;
#pragma unroll
    for (int d = 1; d < 64; d <<= 1) {
        int u = __shfl_up(v, d);
        if (lane >= d) v += u;
    }
    if (lane == 63) wsum[wid] = v;
    __syncthreads();
    int wbase = 0;
#pragma unroll
    for (int w = 0; w < 16; ++w) wbase += (w < wid) ? wsum[w] : 0;
    int incl = wbase + v;
    int excl = incl - tot;
    offsets[base4]     = excl;
    offsets[base4 + 1] = excl + c0;
    offsets[base4 + 2] = excl + c0 + c1;
    offsets[base4 + 3] = excl + c0 + c1 + c2;
    cursor[base4]     = excl;
    cursor[base4 + 1] = excl + c0;
    cursor[base4 + 2] = excl + c0 + c1;
    cursor[base4 + 3] = excl + c0 + c1 + c2;
    if (t == 1023) offsets[V_OUT] = incl;
}

// fill: scatter packed (col,val) pairs in CSR order
__global__ void fill_kernel(const int* __restrict__ rows, const int* __restrict__ cols,
                            const float* __restrict__ vals, int* cursor,
                            float2* __restrict__ pcv) {
    int n = blockIdx.x * blockDim.x + threadIdx.x;
    if (n < NNZ) {
        int r = rows[n];
        int pos = atomicAdd(&cursor[r], 1);
        pcv[pos] = make_float2(__int_as_float(cols[n]), vals[n]);
    }
}

// ---------------- pooling: block = out-row, threads = (batch 16) x (c4 32),
// packed (col,val) CSR stream + float4 x loads ----------------
__global__ __launch_bounds__(512) void pool_kernel(
    const float* __restrict__ x, const int* __restrict__ offsets,
    const float2* __restrict__ pcv, __hip_bfloat16* __restrict__ pool) {
    int r = blockIdx.x;
    int t = threadIdx.x;
    int b = t >> 5, c4 = t & 31;
    int j0 = offsets[r], j1 = offsets[r + 1];
    const float4* xb = (const float4*)x + (size_t)b * (V_IN * 32);
    float4 acc = {0.f, 0.f, 0.f, 0.f};
    for (int j = j0; j < j1; ++j) {
        float2 cv = pcv[j];
        int col = __float_as_int(cv.x);
        float v = cv.y;
        float4 xv = xb[col * 32 + c4];
        acc.x += v * xv.x; acc.y += v * xv.y; acc.z += v * xv.z; acc.w += v * xv.w;
    }
    ushort4 o;
    o.x = __builtin_bit_cast(unsigned short, __float2bfloat16(acc.x));
    o.y = __builtin_bit_cast(unsigned short, __float2bfloat16(acc.y));
    o.z = __builtin_bit_cast(unsigned short, __float2bfloat16(acc.z));
    o.w = __builtin_bit_cast(unsigned short, __float2bfloat16(acc.w));
    ((ushort4*)pool)[((size_t)b * V_OUT + r) * 32 + c4] = o;
}

// ---------------- gathered GEMM: 256x256 tile, 16 waves, balanced K-skip,
// single barrier per K-tile, FULLY UNROLLED K-loop (all addresses/predicates static) ----------------
__global__ __launch_bounds__(1024, 4) void gemm_kernel(
    const __hip_bfloat16* __restrict__ pool,    // [16][4096][128] bf16
    const __hip_bfloat16* __restrict__ wTs,     // [36][16384] bf16, pre-swizzled K-tile images
    const float* __restrict__ bias,             // [256]
    const int* __restrict__ spiral,             // [4096][18]
    float* __restrict__ out)                    // [16][4096][256] f32
{
    // LDS: A slots @0,32768 ; B slots @65536,98304 ; spiral cache @131072 (18432B)
    __shared__ __align__(16) char smem[149504];
    int* spl = (int*)(smem + 131072);

    const int tid  = threadIdx.x;
    const int lane = tid & 63;
    const int wid  = tid >> 6;          // 0..15
    const int wc   = wid & 3;
    const int wm   = (wid >> 2) << 6;   // 0,64,128,192

    const int bid = blockIdx.x;
    const int bm  = ((bid & 7) << 5) + (bid >> 3);   // bijective XCD swizzle (256 = 8*32)
    const int b   = bm >> 4;                          // batch
    const int v0  = (bm & 15) << 8;                   // m-tile origin within batch

    // cache this block's spiral rows in LDS: 256 rows x 18
    for (int i = tid; i < 256 * K_NB; i += 1024) spl[i] = spiral[v0 * K_NB + i];
    asm volatile("s_waitcnt vmcnt(0) lgkmcnt(0)" ::: "memory");
    __builtin_amdgcn_s_barrier();

    const char* poolBytes = (const char*)(pool + (size_t)b * V_OUT * C_IN);
    const char* wTsBytes  = (const char*)wTs;
    // inverse-swizzled source column byte (identical for both 1024-chunks)
    const int sb = ((tid & 7) << 4) ^ (((tid >> 3) & 7) << 4);

    auto stageA = [&](int kt) {          // 2 vmem loads
        const int j   = kt >> 1;
        const int c0b = (kt & 1) << 7;
        char* dst = smem + ((kt & 1) << 15);
#pragma unroll
        for (int ch = 0; ch < 2; ++ch) {
            int flat = (ch << 10) + tid;
            int sidx = spl[(flat >> 3) * K_NB + j];
            GLOAD16(poolBytes + ((size_t)sidx << 8) + (c0b + sb), dst + flat * 16);
        }
    };
    auto stageB = [&](int kt) {          // 2 vmem loads
        const char* src = wTsBytes + ((size_t)kt << 15);
        char* dst = smem + 65536 + ((kt & 1) << 15);
#pragma unroll
        for (int ch = 0; ch < 2; ++ch) {
            int off = ((ch << 10) + tid) << 4;
            GLOAD16(src + off, dst + off);
        }
    };

    // per-lane fragment-read constants
    const int l15   = lane & 15;
    const int swm   = (lane & 7) << 4;          // frag-row&7 == lane&7
    const int klane = (lane >> 4) << 4;         // 0,16,32,48 (byte)
    const int aBase = (wm + l15) << 7;
    const int bOff0 = (((2 * wc)     << 4) + l15) << 7;   // full tile 0
    const int bOff1 = (((2 * wc + 1) << 4) + l15) << 7;   // full tile 1
    const int bOff2 = (((8 + wc)     << 4) + l15) << 7;   // mid tile
    const int bOff3 = (((12 + wc)    << 4) + l15) << 7;   // short tile

    f32x4 acc[4][4] = {};

    stageA(0);
    stageB(0);

#pragma unroll
    for (int kt = 0; kt < NKT; ++kt) {
        const int s = kt & 1;
        const char* As = smem + (s << 15);
        const char* Bs = smem + 65536 + (s << 15);

        // A(kt),B(kt) were issued >= half a tile ago -> this drain is nearly free.
        asm volatile("s_waitcnt vmcnt(0)" ::: "memory");
        __builtin_amdgcn_s_barrier();            // single barrier per K-tile
        __builtin_amdgcn_sched_barrier(0);

        // safe to overwrite slot (kt+1)&1 now: all waves are past the barrier,
        // so all tile-(kt-1) reads of that slot are complete.
        if (kt + 1 < NKT) stageA(kt + 1);

        const bool doMid   = kt < 24;
        const bool doShort = kt < 12;

#pragma unroll
        for (int ks = 0; ks < 2; ++ks) {
            const int kk = (ks * 64 + klane) ^ swm;
            bf16x8 a0 = *(const bf16x8*)(As + aBase + (0 << 11) + kk);
            bf16x8 a1 = *(const bf16x8*)(As + aBase + (1 << 11) + kk);
            bf16x8 a2 = *(const bf16x8*)(As + aBase + (2 << 11) + kk);
            bf16x8 a3 = *(const bf16x8*)(As + aBase + (3 << 11) + kk);
            bf16x8 bb0 = *(const bf16x8*)(Bs + bOff0 + kk);
            bf16x8 bb1 = *(const bf16x8*)(Bs + bOff1 + kk);
            __builtin_amdgcn_s_setprio(1);
            acc[0][0] = MFMA16(a0, bb0, acc[0][0]);
            acc[1][0] = MFMA16(a1, bb0, acc[1][0]);
            acc[2][0] = MFMA16(a2, bb0, acc[2][0]);
            acc[3][0] = MFMA16(a3, bb0, acc[3][0]);
            acc[0][1] = MFMA16(a0, bb1, acc[0][1]);
            acc[1][1] = MFMA16(a1, bb1, acc[1][1]);
            acc[2][1] = MFMA16(a2, bb1, acc[2][1]);
            acc[3][1] = MFMA16(a3, bb1, acc[3][1]);
            __builtin_amdgcn_s_setprio(0);
            if (doMid) {
                bf16x8 bb2 = *(const bf16x8*)(Bs + bOff2 + kk);
                __builtin_amdgcn_s_setprio(1);
                acc[0][2] = MFMA16(a0, bb2, acc[0][2]);
                acc[1][2] = MFMA16(a1, bb2, acc[1][2]);
                acc[2][2] = MFMA16(a2, bb2, acc[2][2]);
                acc[3][2] = MFMA16(a3, bb2, acc[3][2]);
                __builtin_amdgcn_s_setprio(0);
            }
            if (doShort) {
                bf16x8 bb3 = *(const bf16x8*)(Bs + bOff3 + kk);
                __builtin_amdgcn_s_setprio(1);
                acc[0][3] = MFMA16(a0, bb3, acc[0][3]);
                acc[1][3] = MFMA16(a1, bb3, acc[1][3]);
                acc[2][3] = MFMA16(a2, bb3, acc[2][3]);
                acc[3][3] = MFMA16(a3, bb3, acc[3][3]);
                __builtin_amdgcn_s_setprio(0);
            }
            if (ks == 0 && kt + 1 < NKT) stageB(kt + 1);
        }
        // no end-of-tile barrier: next tile's top barrier provides the ordering
    }

    // epilogue: +bias, relu, store f32
    const int nt[4] = {2 * wc, 2 * wc + 1, 8 + wc, 12 + wc};
#pragma unroll
    for (int ni = 0; ni < 4; ++ni) {
        int col = (nt[ni] << 4) + l15;
        float bz = bias[col];
#pragma unroll
        for (int mi = 0; mi < 4; ++mi) {
            int row0 = v0 + wm + mi * 16 + ((lane >> 4) << 2);
#pragma unroll
            for (int r4 = 0; r4 < 4; ++r4) {
                float v = acc[mi][ni][r4] + bz;
                out[((size_t)(b * V_OUT + row0 + r4)) * C_OUT + col] = v > 0.f ? v : 0.f;
            }
        }
    }
}

extern "C" void kernel_launch(void* const* d_in, const int* in_sizes, int n_in,
                              void* d_out, int out_size, void* d_ws, size_t ws_size,
                              hipStream_t stream) {
    const float* x     = (const float*)d_in[0];
    const float* vals  = (const float*)d_in[1];
    const float* W1    = (const float*)d_in[2];
    const float* b1    = (const float*)d_in[3];
    const float* Wd3   = (const float*)d_in[4];
    const float* bd3   = (const float*)d_in[5];
    const float* W2d3  = (const float*)d_in[6];
    const float* b2d3  = (const float*)d_in[7];
    const float* Wf    = (const float*)d_in[8];
    const float* bf    = (const float*)d_in[9];
    const int*   rows  = (const int*)d_in[10];
    const int*   cols  = (const int*)d_in[11];
    const int*   spiral= (const int*)d_in[12];
    float* out = (float*)d_out;

    // workspace layout
    char* ws = (char*)d_ws;
    __hip_bfloat16* pool = (__hip_bfloat16*)ws;                              // 16,777,216 B
    __hip_bfloat16* wTs  = (__hip_bfloat16*)(ws + 16777216);                 //  1,179,648 B
    float* bias          = (float*)(ws + 16777216 + 1179648);                //      1,024 B
    int*   counts        = (int*)(ws + 16777216 + 1179648 + 1024);
    int*   offsets       = counts + V_OUT;          // V_OUT+1 ints
    int*   cursor        = offsets + V_OUT + 4;     // padded
    float2* pcv          = (float2*)(cursor + V_OUT);  // NNZ float2 (8B-aligned)

    hipMemsetAsync(counts, 0, V_OUT * sizeof(int), stream);
    hist_wcomb_kernel<<<64 + NKT * 4 + 1, 256, 0, stream>>>(
        rows, counts, W1, Wd3, W2d3, Wf, b1, bd3, b2d3, bf, wTs, bias);
    scan_kernel<<<1, 1024, 0, stream>>>(counts, offsets, cursor);
    fill_kernel<<<NNZ / 256, 256, 0, stream>>>(rows, cols, vals, cursor, pcv);
    pool_kernel<<<V_OUT, 512, 0, stream>>>(x, offsets, pcv, pool);
    gemm_kernel<<<256, 1024, 0, stream>>>(pool, wTs, bias, spiral, out);
}

// Round 18
// 100.551 us; speedup vs baseline: 1.0720x; 1.0081x over previous
//
#include <hip/hip_runtime.h>
#include <hip/hip_bf16.h>

// Problem constants
#define B_SZ   16
#define V_IN   1024
#define V_OUT  4096
#define C_IN   128
#define C_OUT  256
#define K_NB   18
#define NNZ    16384
#define K_GEMM (K_NB * C_IN)   // 2304
#define BK     64
#define NKT    (K_GEMM / BK)   // 36

typedef __attribute__((ext_vector_type(8))) short bf16x8;   // 8 bf16 = 4 VGPRs
typedef __attribute__((ext_vector_type(4))) float f32x4;

#define GLOAD16(src, dst) __builtin_amdgcn_global_load_lds( \
    (const __attribute__((address_space(1))) unsigned int*)(src), \
    (__attribute__((address_space(3))) unsigned int*)(dst), 16, 0, 0)

#define MFMA16(a_, b_, c_) __builtin_amdgcn_mfma_f32_16x16x32_bf16((a_), (b_), (c_), 0, 0, 0)

// ---------------- fused hist + combined-weight kernel ----------------
__global__ __launch_bounds__(256) void hist_wcomb_kernel(
    const int* __restrict__ rows, int* __restrict__ counts,
    const float* __restrict__ W1, const float* __restrict__ Wd3,
    const float* __restrict__ W2d3, const float* __restrict__ Wf,
    const float* __restrict__ b1, const float* __restrict__ bd3,
    const float* __restrict__ b2d3, const float* __restrict__ bf,
    __hip_bfloat16* __restrict__ wTs, float* __restrict__ bias) {
    const int t = threadIdx.x;
    if (blockIdx.x < 64) {                    // histogram part
        int n = blockIdx.x * 256 + t;
        atomicAdd(&counts[rows[n]], 1);
        return;
    }
    const int blk = blockIdx.x - 64;
    if (blk == NKT * 4) {                     // bias block
        float v = b1[t];
        if (t < 128)      v += bf[t];
        else if (t < 192) v += b2d3[t - 128];
        else              v += bd3[t - 192];
        bias[t] = v;
        return;
    }
    const int kt = blk >> 2, part = blk & 3;
    __shared__ __hip_bfloat16 img[4096];     // 64 cols x 64 k
    const int k0 = kt * 64;

    auto put = [&](int cl, int col7, int kl, float v) {
        int kb    = (kl >> 3) << 4;
        int kslot = kb ^ (col7 << 4);
        int idx   = (((cl << 3) | (kslot >> 4)) << 3) | (kl & 7);
        img[idx] = __float2bfloat16(v);
    };

    if (part < 2) {
        const int cbase = part << 6;                 // cols 0..63 or 64..127 (Wf)
        for (int i = t; i < 4096; i += 256) {
            int kl = i >> 6, cl = i & 63;
            int col = cbase + cl, r = k0 + kl;
            float v = Wf[r * 128 + col];
            if (r < 128) v += W1[r * 256 + col];
            put(cl, col & 7, kl, v);
        }
    } else if (part == 2) {                          // cols 128..191 (W2d3, r<1536)
        for (int i = t; i < 4096; i += 256) {
            int kl = i >> 6, cl = i & 63;
            int r = k0 + kl;
            float v = (r < 1536) ? W2d3[r * 64 + cl] : 0.f;
            if (r < 128) v += W1[r * 256 + 128 + cl];
            put(cl, cl & 7, kl, v);
        }
    } else {                                         // cols 192..255 (Wd3, r<768)
        for (int i = t; i < 4096; i += 256) {
            int kl = i >> 6, cl = i & 63;
            int r = k0 + kl;
            float v = (r < 768) ? Wd3[r * 64 + cl] : 0.f;
            if (r < 128) v += W1[r * 256 + 192 + cl];
            put(cl, cl & 7, kl, v);
        }
    }
    __syncthreads();
    // linear dump: 8 KB quadrant
    ulonglong2* dst = (ulonglong2*)(wTs + (size_t)kt * 16384 + part * 4096);
    const ulonglong2* srcv = (const ulonglong2*)img;
#pragma unroll
    for (int i = t; i < 512; i += 256) dst[i] = srcv[i];
}

// 1024 threads, shfl-based scan of 4096 counts (4 per thread), 1 barrier
__global__ void scan_kernel(const int* __restrict__ counts, int* offsets, int* cursor) {
    __shared__ int wsum[16];
    int t = threadIdx.x;
    int lane = t & 63, wid = t >> 6;
    int base4 = t * 4;
    int c0 = counts[base4], c1 = counts[base4 + 1], c2 = counts[base4 + 2], c3 = counts[base4 + 3];
    int tot = c0 + c1 + c2 + c3;
    int v = tot;
#pragma unroll
    for (int d = 1; d < 64; d <<= 1) {
        int u = __shfl_up(v, d);
        if (lane >= d) v += u;
    }
    if (lane == 63) wsum[wid] = v;
    __syncthreads();
    int wbase = 0;
#pragma unroll
    for (int w = 0; w < 16; ++w) wbase += (w < wid) ? wsum[w] : 0;
    int incl = wbase + v;
    int excl = incl - tot;
    offsets[base4]     = excl;
    offsets[base4 + 1] = excl + c0;
    offsets[base4 + 2] = excl + c0 + c1;
    offsets[base4 + 3] = excl + c0 + c1 + c2;
    cursor[base4]     = excl;
    cursor[base4 + 1] = excl + c0;
    cursor[base4 + 2] = excl + c0 + c1;
    cursor[base4 + 3] = excl + c0 + c1 + c2;
    if (t == 1023) offsets[V_OUT] = incl;
}

// fill: scatter packed (col,val) pairs in CSR order
__global__ void fill_kernel(const int* __restrict__ rows, const int* __restrict__ cols,
                            const float* __restrict__ vals, int* cursor,
                            float2* __restrict__ pcv) {
    int n = blockIdx.x * blockDim.x + threadIdx.x;
    if (n < NNZ) {
        int r = rows[n];
        int pos = atomicAdd(&cursor[r], 1);
        pcv[pos] = make_float2(__int_as_float(cols[n]), vals[n]);
    }
}

// ---------------- pooling ----------------
__global__ __launch_bounds__(512) void pool_kernel(
    const float* __restrict__ x, const int* __restrict__ offsets,
    const float2* __restrict__ pcv, __hip_bfloat16* __restrict__ pool) {
    int r = blockIdx.x;
    int t = threadIdx.x;
    int b = t >> 5, c4 = t & 31;
    int j0 = offsets[r], j1 = offsets[r + 1];
    const float4* xb = (const float4*)x + (size_t)b * (V_IN * 32);
    float4 acc = {0.f, 0.f, 0.f, 0.f};
    for (int j = j0; j < j1; ++j) {
        float2 cv = pcv[j];
        int col = __float_as_int(cv.x);
        float v = cv.y;
        float4 xv = xb[col * 32 + c4];
        acc.x += v * xv.x; acc.y += v * xv.y; acc.z += v * xv.z; acc.w += v * xv.w;
    }
    ushort4 o;
    o.x = __builtin_bit_cast(unsigned short, __float2bfloat16(acc.x));
    o.y = __builtin_bit_cast(unsigned short, __float2bfloat16(acc.y));
    o.z = __builtin_bit_cast(unsigned short, __float2bfloat16(acc.z));
    o.w = __builtin_bit_cast(unsigned short, __float2bfloat16(acc.w));
    ((ushort4*)pool)[((size_t)b * V_OUT + r) * 32 + c4] = o;
}

// ---------------- gathered GEMM: 256x256 tile, 16 waves, balanced K-skip,
// single barrier per K-tile, 3-phase K-loop (branch-free bodies) with unroll 2 ----------------
__global__ __launch_bounds__(1024, 4) void gemm_kernel(
    const __hip_bfloat16* __restrict__ pool,    // [16][4096][128] bf16
    const __hip_bfloat16* __restrict__ wTs,     // [36][16384] bf16, pre-swizzled K-tile images
    const float* __restrict__ bias,             // [256]
    const int* __restrict__ spiral,             // [4096][18]
    float* __restrict__ out)                    // [16][4096][256] f32
{
    // LDS: A slots @0,32768 ; B slots @65536,98304 ; spiral cache @131072 (18432B)
    __shared__ __align__(16) char smem[149504];
    int* spl = (int*)(smem + 131072);

    const int tid  = threadIdx.x;
    const int lane = tid & 63;
    const int wid  = tid >> 6;          // 0..15
    const int wc   = wid & 3;
    const int wm   = (wid >> 2) << 6;   // 0,64,128,192

    const int bid = blockIdx.x;
    const int bm  = ((bid & 7) << 5) + (bid >> 3);   // bijective XCD swizzle (256 = 8*32)
    const int b   = bm >> 4;                          // batch
    const int v0  = (bm & 15) << 8;                   // m-tile origin within batch

    // cache this block's spiral rows in LDS: 256 rows x 18
    for (int i = tid; i < 256 * K_NB; i += 1024) spl[i] = spiral[v0 * K_NB + i];
    asm volatile("s_waitcnt vmcnt(0) lgkmcnt(0)" ::: "memory");
    __builtin_amdgcn_s_barrier();

    const char* poolBytes = (const char*)(pool + (size_t)b * V_OUT * C_IN);
    const char* wTsBytes  = (const char*)wTs;
    // inverse-swizzled source column byte (identical for both 1024-chunks)
    const int sb = ((tid & 7) << 4) ^ (((tid >> 3) & 7) << 4);

    auto stageA = [&](int kt) {          // 2 vmem loads
        const int j   = kt >> 1;
        const int c0b = (kt & 1) << 7;
        char* dst = smem + ((kt & 1) << 15);
#pragma unroll
        for (int ch = 0; ch < 2; ++ch) {
            int flat = (ch << 10) + tid;
            int sidx = spl[(flat >> 3) * K_NB + j];
            GLOAD16(poolBytes + ((size_t)sidx << 8) + (c0b + sb), dst + flat * 16);
        }
    };
    auto stageB = [&](int kt) {          // 2 vmem loads
        const char* src = wTsBytes + ((size_t)kt << 15);
        char* dst = smem + 65536 + ((kt & 1) << 15);
#pragma unroll
        for (int ch = 0; ch < 2; ++ch) {
            int off = ((ch << 10) + tid) << 4;
            GLOAD16(src + off, dst + off);
        }
    };

    // per-lane fragment-read constants
    const int l15   = lane & 15;
    const int swm   = (lane & 7) << 4;          // frag-row&7 == lane&7
    const int klane = (lane >> 4) << 4;         // 0,16,32,48 (byte)
    const int aBase = (wm + l15) << 7;
    const int bOff0 = (((2 * wc)     << 4) + l15) << 7;   // full tile 0
    const int bOff1 = (((2 * wc + 1) << 4) + l15) << 7;   // full tile 1
    const int bOff2 = (((8 + wc)     << 4) + l15) << 7;   // mid tile
    const int bOff3 = (((12 + wc)    << 4) + l15) << 7;   // short tile

    f32x4 acc[4][4] = {};

    stageA(0);
    stageB(0);

// Tile body: DOMID/DOSHORT are compile-time literals per phase -> branch-free.
#define TILE_BODY(KT, DOMID, DOSHORT)                                          \
    {                                                                          \
        const int s_ = (KT) & 1;                                               \
        const char* As = smem + (s_ << 15);                                    \
        const char* Bs = smem + 65536 + (s_ << 15);                            \
        asm volatile("s_waitcnt vmcnt(0)" ::: "memory");                       \
        __builtin_amdgcn_s_barrier();                                          \
        __builtin_amdgcn_sched_barrier(0);                                     \
        if ((KT) + 1 < NKT) stageA((KT) + 1);                                  \
        _Pragma("unroll")                                                      \
        for (int ks = 0; ks < 2; ++ks) {                                       \
            const int kk = (ks * 64 + klane) ^ swm;                            \
            bf16x8 a0 = *(const bf16x8*)(As + aBase + (0 << 11) + kk);         \
            bf16x8 a1 = *(const bf16x8*)(As + aBase + (1 << 11) + kk);         \
            bf16x8 a2 = *(const bf16x8*)(As + aBase + (2 << 11) + kk);         \
            bf16x8 a3 = *(const bf16x8*)(As + aBase + (3 << 11) + kk);         \
            bf16x8 bb0 = *(const bf16x8*)(Bs + bOff0 + kk);                    \
            bf16x8 bb1 = *(const bf16x8*)(Bs + bOff1 + kk);                    \
            __builtin_amdgcn_s_setprio(1);                                     \
            acc[0][0] = MFMA16(a0, bb0, acc[0][0]);                            \
            acc[1][0] = MFMA16(a1, bb0, acc[1][0]);                            \
            acc[2][0] = MFMA16(a2, bb0, acc[2][0]);                            \
            acc[3][0] = MFMA16(a3, bb0, acc[3][0]);                            \
            acc[0][1] = MFMA16(a0, bb1, acc[0][1]);                            \
            acc[1][1] = MFMA16(a1, bb1, acc[1][1]);                            \
            acc[2][1] = MFMA16(a2, bb1, acc[2][1]);                            \
            acc[3][1] = MFMA16(a3, bb1, acc[3][1]);                            \
            __builtin_amdgcn_s_setprio(0);                                     \
            if (DOMID) {                                                       \
                bf16x8 bb2 = *(const bf16x8*)(Bs + bOff2 + kk);                \
                __builtin_amdgcn_s_setprio(1);                                 \
                acc[0][2] = MFMA16(a0, bb2, acc[0][2]);                        \
                acc[1][2] = MFMA16(a1, bb2, acc[1][2]);                        \
                acc[2][2] = MFMA16(a2, bb2, acc[2][2]);                        \
                acc[3][2] = MFMA16(a3, bb2, acc[3][2]);                        \
                __builtin_amdgcn_s_setprio(0);                                 \
            }                                                                  \
            if (DOSHORT) {                                                     \
                bf16x8 bb3 = *(const bf16x8*)(Bs + bOff3 + kk);                \
                __builtin_amdgcn_s_setprio(1);                                 \
                acc[0][3] = MFMA16(a0, bb3, acc[0][3]);                        \
                acc[1][3] = MFMA16(a1, bb3, acc[1][3]);                        \
                acc[2][3] = MFMA16(a2, bb3, acc[2][3]);                        \
                acc[3][3] = MFMA16(a3, bb3, acc[3][3]);                        \
                __builtin_amdgcn_s_setprio(0);                                 \
            }                                                                  \
            if (ks == 0 && (KT) + 1 < NKT) stageB((KT) + 1);                   \
        }                                                                      \
    }

#pragma unroll 2
    for (int kt = 0; kt < 12; ++kt) TILE_BODY(kt, 1, 1)
#pragma unroll 2
    for (int kt = 12; kt < 24; ++kt) TILE_BODY(kt, 1, 0)
#pragma unroll 2
    for (int kt = 24; kt < 36; ++kt) TILE_BODY(kt, 0, 0)
#undef TILE_BODY

    // epilogue: +bias, relu, store f32
    const int nt[4] = {2 * wc, 2 * wc + 1, 8 + wc, 12 + wc};
#pragma unroll
    for (int ni = 0; ni < 4; ++ni) {
        int col = (nt[ni] << 4) + l15;
        float bz = bias[col];
#pragma unroll
        for (int mi = 0; mi < 4; ++mi) {
            int row0 = v0 + wm + mi * 16 + ((lane >> 4) << 2);
#pragma unroll
            for (int r4 = 0; r4 < 4; ++r4) {
                float v = acc[mi][ni][r4] + bz;
                out[((size_t)(b * V_OUT + row0 + r4)) * C_OUT + col] = v > 0.f ? v : 0.f;
            }
        }
    }
}

extern "C" void kernel_launch(void* const* d_in, const int* in_sizes, int n_in,
                              void* d_out, int out_size, void* d_ws, size_t ws_size,
                              hipStream_t stream) {
    const float* x     = (const float*)d_in[0];
    const float* vals  = (const float*)d_in[1];
    const float* W1    = (const float*)d_in[2];
    const float* b1    = (const float*)d_in[3];
    const float* Wd3   = (const float*)d_in[4];
    const float* bd3   = (const float*)d_in[5];
    const float* W2d3  = (const float*)d_in[6];
    const float* b2d3  = (const float*)d_in[7];
    const float* Wf    = (const float*)d_in[8];
    const float* bf    = (const float*)d_in[9];
    const int*   rows  = (const int*)d_in[10];
    const int*   cols  = (const int*)d_in[11];
    const int*   spiral= (const int*)d_in[12];
    float* out = (float*)d_out;

    // workspace layout
    char* ws = (char*)d_ws;
    __hip_bfloat16* pool = (__hip_bfloat16*)ws;                              // 16,777,216 B
    __hip_bfloat16* wTs  = (__hip_bfloat16*)(ws + 16777216);                 //  1,179,648 B
    float* bias          = (float*)(ws + 16777216 + 1179648);                //      1,024 B
    int*   counts        = (int*)(ws + 16777216 + 1179648 + 1024);
    int*   offsets       = counts + V_OUT;          // V_OUT+1 ints
    int*   cursor        = offsets + V_OUT + 4;     // padded
    float2* pcv          = (float2*)(cursor + V_OUT);  // NNZ float2 (8B-aligned)

    hipMemsetAsync(counts, 0, V_OUT * sizeof(int), stream);
    hist_wcomb_kernel<<<64 + NKT * 4 + 1, 256, 0, stream>>>(
        rows, counts, W1, Wd3, W2d3, Wf, b1, bd3, b2d3, bf, wTs, bias);
    scan_kernel<<<1, 1024, 0, stream>>>(counts, offsets, cursor);
    fill_kernel<<<NNZ / 256, 256, 0, stream>>>(rows, cols, vals, cursor, pcv);
    pool_kernel<<<V_OUT, 512, 0, stream>>>(x, offsets, pcv, pool);
    gemm_kernel<<<256, 1024, 0, stream>>>(pool, wTs, bias, spiral, out);
}